// Round 1
// baseline (640.827 us; speedup 1.0000x reference)
//
#include <hip/hip_runtime.h>

// Problem constants
#define B_ 4
#define C_ 256
#define O_ 256
#define H_ 64
#define W_ 64
#define HW 4096
#define NOFF 18     // 2*K*K offset channels
#define CK 2304     // C_*9, K-dim of main contraction
#define CC 4        // c-chunk for GEMM staging

// ---------------------------------------------------------------------------
// Kernel 1: offset-predictor conv (3x3, pad 1) -> offs[b][pixel][18]
// Block: (64 px, 8 c-groups); grid: B_*H_ (one row per block).
// ---------------------------------------------------------------------------
__global__ __launch_bounds__(512) void offset_conv_kernel(
    const float* __restrict__ x, const float* __restrict__ w_off,
    const float* __restrict__ b_off, float* __restrict__ offs)
{
    __shared__ float red[8][64][19];   // padded stride 19 -> conflict-free
    const int tx = threadIdx.x;        // pixel w (0..63)
    const int ty = threadIdx.y;        // c-group (0..7), 32 channels each
    const int bid = blockIdx.x;        // b*64 + h
    const int b = bid >> 6, h = bid & 63;

    float acc[NOFF];
#pragma unroll
    for (int i = 0; i < NOFF; ++i) acc[i] = 0.f;

    const int c0 = ty * 32;
    for (int ci = 0; ci < 32; ++ci) {
        const int c = c0 + ci;
        const float* xp = x + ((size_t)(b * C_ + c)) * HW;
        const float* wp = w_off + c * 9;        // w_off[oc][c][kk] = oc*CK + c*9 + kk
#pragma unroll
        for (int ky = 0; ky < 3; ++ky) {
            const int y = h + ky - 1;
            if (y < 0 || y >= H_) continue;
            const float* row = xp + y * W_;
#pragma unroll
            for (int kx = 0; kx < 3; ++kx) {
                const int xw = tx + kx - 1;
                const float xv = (xw >= 0 && xw < W_) ? row[xw] : 0.f;
                const int kk = ky * 3 + kx;
#pragma unroll
                for (int oc = 0; oc < NOFF; ++oc)
                    acc[oc] += xv * wp[oc * CK + kk];
            }
        }
    }
#pragma unroll
    for (int oc = 0; oc < NOFF; ++oc) red[ty][tx][oc] = acc[oc];
    __syncthreads();

    const int tid = ty * 64 + tx;
    for (int idx = tid; idx < 64 * NOFF; idx += 512) {
        const int w = idx / NOFF, oc = idx % NOFF;
        float s = 0.f;
#pragma unroll
        for (int g = 0; g < 8; ++g) s += red[g][w][oc];
        offs[((size_t)(b * HW) + h * 64 + w) * NOFF + oc] = s + b_off[oc];
    }
}

// ---------------------------------------------------------------------------
// Kernel 2: fused bilinear sampling + main contraction (implicit GEMM).
// Block: 256 threads computes out[b, ob..ob+128, h, 0..64].
// Grid: (h=64, b=4, o-half=2).
// Thread tile: 4 o (stride 32) x 8 p (stride 8) fp32 accumulators.
// ---------------------------------------------------------------------------
__global__ __launch_bounds__(256) void deform_gemm_kernel(
    const float* __restrict__ x, const float* __restrict__ offs,
    const float* __restrict__ w_def, const float* __restrict__ b_def,
    float* __restrict__ out)
{
    __shared__ int   midx[9][64][4];     // 9.2 KB  bilinear corner indices
    __shared__ float mwgt[9][64][4];     // 9.2 KB  bilinear corner weights
    __shared__ float S[CC][9][64];       // 9.2 KB  sampled chunk
    __shared__ float Wl[128][37];        // 18.9 KB W chunk (36 used, pad 37)

    const int tid = threadIdx.x;
    const int h = blockIdx.x;            // output row
    const int b = blockIdx.y;
    const int ob = blockIdx.z * 128;     // o base

    // ---- bilinear sampling metadata (c-independent; computed once) ----
    for (int s = tid; s < 9 * 64; s += 256) {
        const int kk = s >> 6, p = s & 63;
        const float2 dv = *reinterpret_cast<const float2*>(
            offs + ((size_t)(b * HW) + h * 64 + p) * NOFF + 2 * kk);
        const int ky = kk / 3, kx = kk % 3;
        const float py = (float)(h + ky - 1) + dv.x;   // channel 2k   = dy
        const float px = (float)(p + kx - 1) + dv.y;   // channel 2k+1 = dx
        const float y0f = floorf(py), x0f = floorf(px);
        const float ly = py - y0f, lx = px - x0f;
        const int y0 = (int)y0f, x0 = (int)x0f;
#pragma unroll
        for (int my = 0; my < 2; ++my) {
#pragma unroll
            for (int mx = 0; mx < 2; ++mx) {
                const int yi = y0 + my, xi = x0 + mx;
                const bool ok = (yi >= 0) && (yi < H_) && (xi >= 0) && (xi < W_);
                const float wy = my ? ly : 1.f - ly;
                const float wx = mx ? lx : 1.f - lx;
                const int yc = min(max(yi, 0), H_ - 1);
                const int xc = min(max(xi, 0), W_ - 1);
                midx[kk][p][my * 2 + mx] = yc * W_ + xc;
                mwgt[kk][p][my * 2 + mx] = ok ? wy * wx : 0.f;
            }
        }
    }

    float acc[4][8];
#pragma unroll
    for (int i = 0; i < 4; ++i)
#pragma unroll
        for (int j = 0; j < 8; ++j) acc[i][j] = 0.f;

    const int pg = tid & 7;        // p = pg + 8j
    const int og = tid >> 3;       // o = ob + og + 32i
    const float* xb = x + (size_t)(b * C_) * HW;

    for (int c0 = 0; c0 < C_; c0 += CC) {
        __syncthreads();   // meta ready (1st iter) / previous S,W consumed

        // ---- stage W chunk: 128 o x 36 k as float4 ----
        for (int s = tid; s < 128 * 9; s += 256) {
            const int o = s / 9, q = s % 9;
            const float4 v = *reinterpret_cast<const float4*>(
                w_def + (size_t)(ob + o) * CK + c0 * 9 + q * 4);
            Wl[o][q * 4 + 0] = v.x;
            Wl[o][q * 4 + 1] = v.y;
            Wl[o][q * 4 + 2] = v.z;
            Wl[o][q * 4 + 3] = v.w;
        }

        // ---- stage S chunk: CC c x 9 k x 64 p bilinear samples ----
#pragma unroll
        for (int r = 0; r < 9; ++r) {
            const int s = tid + 256 * r;          // 0..2303
            const int cc = s / (9 * 64);
            const int rem = s % (9 * 64);
            const int kk = rem >> 6, p = rem & 63;
            const float* xc = xb + (size_t)(c0 + cc) * HW;
            const int* mi = midx[kk][p];
            const float* mw = mwgt[kk][p];
            const float v = mw[0] * xc[mi[0]] + mw[1] * xc[mi[1]] +
                            mw[2] * xc[mi[2]] + mw[3] * xc[mi[3]];
            S[cc][kk][p] = v;
        }
        __syncthreads();

        // ---- micro-GEMM: 4o x 8p per thread ----
        for (int cc = 0; cc < CC; ++cc) {
#pragma unroll
            for (int kk = 0; kk < 9; ++kk) {
                float sv[8], wv[4];
#pragma unroll
                for (int j = 0; j < 8; ++j) sv[j] = S[cc][kk][pg + 8 * j];
#pragma unroll
                for (int i = 0; i < 4; ++i) wv[i] = Wl[og + 32 * i][cc * 9 + kk];
#pragma unroll
                for (int i = 0; i < 4; ++i)
#pragma unroll
                    for (int j = 0; j < 8; ++j)
                        acc[i][j] += wv[i] * sv[j];
            }
        }
    }

    // ---- epilogue: bias + store ----
#pragma unroll
    for (int i = 0; i < 4; ++i) {
        const int o = ob + og + 32 * i;
        const float bias = b_def[o];
        float* op = out + ((size_t)(b * O_ + o) * H_ + h) * W_;
#pragma unroll
        for (int j = 0; j < 8; ++j) op[pg + 8 * j] = acc[i][j] + bias;
    }
}

// ---------------------------------------------------------------------------
extern "C" void kernel_launch(void* const* d_in, const int* in_sizes, int n_in,
                              void* d_out, int out_size, void* d_ws, size_t ws_size,
                              hipStream_t stream) {
    const float* x     = (const float*)d_in[0];
    const float* w_off = (const float*)d_in[1];
    const float* b_off = (const float*)d_in[2];
    const float* w_def = (const float*)d_in[3];
    const float* b_def = (const float*)d_in[4];
    float* out  = (float*)d_out;
    float* offs = (float*)d_ws;    // B_*HW*NOFF floats = 1.18 MB scratch

    offset_conv_kernel<<<dim3(B_ * H_), dim3(64, 8), 0, stream>>>(
        x, w_off, b_off, offs);
    deform_gemm_kernel<<<dim3(H_, B_, 2), dim3(256), 0, stream>>>(
        x, offs, w_def, b_def, out);
}

// Round 2
// 357.361 us; speedup vs baseline: 1.7932x; 1.7932x over previous
//
#include <hip/hip_runtime.h>

#define B_ 4
#define C_ 256
#define O_ 256
#define H_ 64
#define W_ 64
#define HW 4096
#define NOFF 18
#define CK 2304

typedef __bf16 bf16x8 __attribute__((ext_vector_type(8)));
typedef float f32x4 __attribute__((ext_vector_type(4)));

// ---------------------------------------------------------------------------
// wprep_off: wt_off[c][kk][20] = w_off[oc][c][kk]  (oc contiguous, padded 20)
// grid 9 x 256; thread = one (c,kk)
// ---------------------------------------------------------------------------
__global__ __launch_bounds__(256) void wprep_off_kernel(
    const float* __restrict__ w_off, float* __restrict__ wt_off)
{
    const int id = blockIdx.x * 256 + threadIdx.x;   // 0..2303
    const int c = id / 9, kk = id % 9;
#pragma unroll
    for (int oc = 0; oc < NOFF; ++oc)
        wt_off[(size_t)id * 20 + oc] = w_off[(size_t)oc * CK + c * 9 + kk];
}

// ---------------------------------------------------------------------------
// wprep_def: Wt4[ch][o*8 + (g^(o&7))] = bf16x8 of w_def[o][cg*64+g*8+j][kk]
// ch = kk*4 + cg (36 chunks); pre-swizzled linear LDS image per chunk.
// grid 36 x 256
// ---------------------------------------------------------------------------
__global__ __launch_bounds__(256) void wprep_def_kernel(
    const float* __restrict__ w_def, uint4* __restrict__ Wt4)
{
    const int blk = blockIdx.x;            // chunk id 0..35
    const int kk = blk >> 2, cg = blk & 3;
    const int t = threadIdx.x;
#pragma unroll
    for (int r = 0; r < 8; ++r) {
        const int gid = t + 256 * r;       // 0..2047
        const int o = gid >> 3, g = gid & 7;
        bf16x8 v;
#pragma unroll
        for (int j = 0; j < 8; ++j) {
            const int c = cg * 64 + g * 8 + j;
            v[j] = (__bf16)w_def[(size_t)o * CK + c * 9 + kk];
        }
        Wt4[(size_t)blk * 2048 + o * 8 + (g ^ (o & 7))] = __builtin_bit_cast(uint4, v);
    }
}

// ---------------------------------------------------------------------------
// Kernel 1: offset conv (fp32). block (64px, 8 c-groups), grid B*H.
// Weights read as contiguous float4 broadcasts from wt_off.
// ---------------------------------------------------------------------------
__global__ __launch_bounds__(512) void offset_conv_kernel(
    const float* __restrict__ x, const float* __restrict__ wt_off,
    const float* __restrict__ b_off, float* __restrict__ offs)
{
    __shared__ float red[8][64][18];
    const int tx = threadIdx.x, ty = threadIdx.y;
    const int b = blockIdx.x >> 6, h = blockIdx.x & 63;

    float acc[NOFF];
#pragma unroll
    for (int i = 0; i < NOFF; ++i) acc[i] = 0.f;

    const float* xp = x + ((size_t)(b * C_) + ty * 32) * HW;
    for (int ci = 0; ci < 32; ++ci) {
        const int c = ty * 32 + ci;
        float xv[9];
#pragma unroll
        for (int ky = 0; ky < 3; ++ky) {
            const int row = h + ky - 1;
            const bool rv = (row >= 0) && (row < H_);
            const int rowc = min(max(row, 0), H_ - 1);
#pragma unroll
            for (int kx = 0; kx < 3; ++kx) {
                const int col = tx + kx - 1;
                const bool cv = (col >= 0) && (col < W_);
                const int colc = min(max(col, 0), W_ - 1);
                const float v = xp[(size_t)ci * HW + rowc * W_ + colc];
                xv[ky * 3 + kx] = (rv && cv) ? v : 0.f;
            }
        }
        const float4* wv = (const float4*)(wt_off + (size_t)c * 9 * 20);
#pragma unroll
        for (int kk = 0; kk < 9; ++kk) {
            float wreg[20];
            const float4* wk = wv + kk * 5;
#pragma unroll
            for (int q = 0; q < 5; ++q) {
                const float4 f = wk[q];
                wreg[q * 4 + 0] = f.x; wreg[q * 4 + 1] = f.y;
                wreg[q * 4 + 2] = f.z; wreg[q * 4 + 3] = f.w;
            }
#pragma unroll
            for (int oc = 0; oc < NOFF; ++oc)
                acc[oc] += xv[kk] * wreg[oc];
        }
    }
#pragma unroll
    for (int oc = 0; oc < NOFF; ++oc) red[ty][tx][oc] = acc[oc];
    __syncthreads();

    const int t = ty * 64 + tx;
    for (int i = t; i < 64 * NOFF; i += 512) {
        const int px = i / NOFF, oc = i % NOFF;
        float s = 0.f;
#pragma unroll
        for (int g = 0; g < 8; ++g) s += red[g][px][oc];
        offs[((size_t)(b * HW) + h * 64 + px) * NOFF + oc] = s + b_off[oc];
    }
}

// ---------------------------------------------------------------------------
// Kernel 2: fused bilinear sampling + bf16 MFMA contraction.
// grid (64 h, 4 b), 512 threads (8 waves). Block tile 256o x 64p.
// Wave tile 64o x 32p = 4x2 frags of 16x16x32. 36 chunks (kk, 64c) x 2 ksteps.
// ---------------------------------------------------------------------------
__global__ __launch_bounds__(512, 2) void deform_mfma_kernel(
    const float* __restrict__ x, const float* __restrict__ offs,
    const uint4* __restrict__ Wt4, const float* __restrict__ b_def,
    float* __restrict__ out)
{
    __shared__ uint4 Wl4[2048];   // [256 o][8 gran], granule pos = g ^ (o&7)
    __shared__ uint4 Sl4[512];    // [64 p][8 gran], granule pos = g ^ (p&7)

    const int t = threadIdx.x;
    const int h = blockIdx.x, b = blockIdx.y;
    const int lane = t & 63;
    const int w = t >> 6;
    const int wo = w >> 1, wp = w & 1;
    const int l15 = lane & 15, l4 = lane >> 4;

    const int sp = t & 63;          // staging pixel
    const int sg = t >> 6;          // staging c-granule (0..7)

    const float* xb = x + (size_t)b * C_ * HW;
    const float* ob = offs + ((size_t)(b * HW) + h * 64 + sp) * NOFF;

    f32x4 acc[4][2];
#pragma unroll
    for (int i = 0; i < 4; ++i)
#pragma unroll
        for (int j = 0; j < 2; ++j) acc[i][j] = f32x4{0.f, 0.f, 0.f, 0.f};

    for (int ch = 0; ch < 36; ++ch) {
        const int kk = ch >> 2, cg = ch & 3;
        __syncthreads();            // previous chunk's reads done
        // ---- stage W (pre-swizzled linear image: straight copy) ----
        const uint4* wsrc = Wt4 + (size_t)ch * 2048;
#pragma unroll
        for (int r = 0; r < 4; ++r)
            Wl4[t + 512 * r] = wsrc[t + 512 * r];
        // ---- bilinear meta for (kk, sp), recomputed per chunk ----
        const int ky = kk / 3, kx = kk - 3 * ky;
        const float dy = ob[2 * kk], dx = ob[2 * kk + 1];
        const float py = (float)(h + ky - 1) + dy;
        const float px = (float)(sp + kx - 1) + dx;
        const float y0f = floorf(py), x0f = floorf(px);
        const float ly = py - y0f, lx = px - x0f;
        const int y0 = (int)y0f, x0 = (int)x0f;
        const int y1 = y0 + 1, x1 = x0 + 1;
        const bool vy0 = (y0 >= 0) && (y0 < H_), vy1 = (y1 >= 0) && (y1 < H_);
        const bool vx0 = (x0 >= 0) && (x0 < W_), vx1 = (x1 >= 0) && (x1 < W_);
        const int y0c = min(max(y0, 0), H_ - 1), y1c = min(max(y1, 0), H_ - 1);
        const int x0c = min(max(x0, 0), W_ - 1), x1c = min(max(x1, 0), W_ - 1);
        const int i0 = y0c * W_ + x0c, i1 = y0c * W_ + x1c;
        const int i2 = y1c * W_ + x0c, i3 = y1c * W_ + x1c;
        const float w0 = (vy0 && vx0) ? (1.f - ly) * (1.f - lx) : 0.f;
        const float w1 = (vy0 && vx1) ? (1.f - ly) * lx : 0.f;
        const float w2 = (vy1 && vx0) ? ly * (1.f - lx) : 0.f;
        const float w3 = (vy1 && vx1) ? ly * lx : 0.f;
        // ---- stage S: 8 channels for (sp, kk) ----
        const float* pl = xb + (size_t)(cg * 64 + sg * 8) * HW;
        bf16x8 sv;
#pragma unroll
        for (int j = 0; j < 8; ++j) {
            const float* p = pl + (size_t)j * HW;
            const float v = w0 * p[i0] + w1 * p[i1] + w2 * p[i2] + w3 * p[i3];
            sv[j] = (__bf16)v;
        }
        Sl4[sp * 8 + (sg ^ (sp & 7))] = __builtin_bit_cast(uint4, sv);
        __syncthreads();            // staging visible
        // ---- compute: 2 K-steps of 32 ----
#pragma unroll
        for (int st = 0; st < 2; ++st) {
            const int g = st * 4 + l4;
            bf16x8 aF[4], bF[2];
#pragma unroll
            for (int i = 0; i < 4; ++i) {
                const int row = wo * 64 + i * 16 + l15;
                aF[i] = __builtin_bit_cast(bf16x8, Wl4[row * 8 + (g ^ (row & 7))]);
            }
#pragma unroll
            for (int j = 0; j < 2; ++j) {
                const int pr = wp * 32 + j * 16 + l15;
                bF[j] = __builtin_bit_cast(bf16x8, Sl4[pr * 8 + (g ^ (pr & 7))]);
            }
#pragma unroll
            for (int i = 0; i < 4; ++i)
#pragma unroll
                for (int j = 0; j < 2; ++j)
                    acc[i][j] = __builtin_amdgcn_mfma_f32_16x16x32_bf16(
                        aF[i], bF[j], acc[i][j], 0, 0, 0);
        }
    }
    // ---- epilogue: bias + store (C/D: row=(l>>4)*4+r, col=l&15) ----
#pragma unroll
    for (int i = 0; i < 4; ++i) {
#pragma unroll
        for (int r = 0; r < 4; ++r) {
            const int o = wo * 64 + i * 16 + l4 * 4 + r;
            const float bias = b_def[o];
#pragma unroll
            for (int j = 0; j < 2; ++j) {
                const int p = wp * 32 + j * 16 + l15;
                out[(((size_t)(b * O_ + o)) * H_ + h) * W_ + p] = acc[i][j][r] + bias;
            }
        }
    }
}

// ---------------------------------------------------------------------------
extern "C" void kernel_launch(void* const* d_in, const int* in_sizes, int n_in,
                              void* d_out, int out_size, void* d_ws, size_t ws_size,
                              hipStream_t stream) {
    const float* x     = (const float*)d_in[0];
    const float* w_off = (const float*)d_in[1];
    const float* b_off = (const float*)d_in[2];
    const float* w_def = (const float*)d_in[3];
    const float* b_def = (const float*)d_in[4];
    float* out = (float*)d_out;

    // ws layout: offs (294912 f) | wt_off (46080 f) | Wt4 (73728 uint4) = 2.43 MB
    float* offs   = (float*)d_ws;
    float* wt_off = offs + (size_t)B_ * HW * NOFF;
    uint4* Wt4    = (uint4*)(wt_off + 2304 * 20);

    wprep_off_kernel<<<9, 256, 0, stream>>>(w_off, wt_off);
    wprep_def_kernel<<<36, 256, 0, stream>>>(w_def, Wt4);
    offset_conv_kernel<<<256, dim3(64, 8), 0, stream>>>(x, wt_off, b_off, offs);
    deform_mfma_kernel<<<dim3(H_, B_), 512, 0, stream>>>(x, offs, Wt4, b_def, out);
}

// Round 3
// 313.466 us; speedup vs baseline: 2.0443x; 1.1400x over previous
//
#include <hip/hip_runtime.h>

#define B_ 4
#define C_ 256
#define O_ 256
#define H_ 64
#define W_ 64
#define HW 4096
#define NOFF 18
#define CK 2304

typedef __bf16 bf16x8 __attribute__((ext_vector_type(8)));
typedef float f32x4 __attribute__((ext_vector_type(4)));

// ---------------------------------------------------------------------------
// wprep_off: wt_off[c][kk][20] = w_off[oc][c][kk]  (oc contiguous, padded 20)
// ---------------------------------------------------------------------------
__global__ __launch_bounds__(256) void wprep_off_kernel(
    const float* __restrict__ w_off, float* __restrict__ wt_off)
{
    const int id = blockIdx.x * 256 + threadIdx.x;   // 0..2303
    const int c = id / 9, kk = id % 9;
#pragma unroll
    for (int oc = 0; oc < NOFF; ++oc)
        wt_off[(size_t)id * 20 + oc] = w_off[(size_t)oc * CK + c * 9 + kk];
}

// ---------------------------------------------------------------------------
// wprep_def: pre-swizzled bf16 W image per (kk, cg) chunk.
// Wt4[ch][o*8 + (g^(o&7))] = bf16x8 of w_def[o][cg*64+g*8+j][kk]
// ---------------------------------------------------------------------------
__global__ __launch_bounds__(256) void wprep_def_kernel(
    const float* __restrict__ w_def, uint4* __restrict__ Wt4)
{
    const int blk = blockIdx.x;            // chunk id 0..35
    const int kk = blk >> 2, cg = blk & 3;
    const int t = threadIdx.x;
#pragma unroll
    for (int r = 0; r < 8; ++r) {
        const int gid = t + 256 * r;       // 0..2047
        const int o = gid >> 3, g = gid & 7;
        bf16x8 v;
#pragma unroll
        for (int j = 0; j < 8; ++j) {
            const int c = cg * 64 + g * 8 + j;
            v[j] = (__bf16)w_def[(size_t)o * CK + c * 9 + kk];
        }
        Wt4[(size_t)blk * 2048 + o * 8 + (g ^ (o & 7))] = __builtin_bit_cast(uint4, v);
    }
}

// ---------------------------------------------------------------------------
// Kernel 1a: offset conv partials. 1024 blocks (XCD-swizzled), 256 threads.
// Block = (b, h, cq); ty (0..3) covers 16 channels of the 64-ch quarter.
// ---------------------------------------------------------------------------
__global__ __launch_bounds__(256, 4) void offset_conv_part_kernel(
    const float* __restrict__ x, const float* __restrict__ wt_off,
    float* __restrict__ part)
{
    // bijective XCD swizzle: XCD (i&7) gets 128 contiguous logical blocks
    const int i = blockIdx.x;
    const int l = ((i & 7) << 7) + (i >> 3);
    const int b = l >> 8;
    const int rem = l & 255;
    const int h = rem >> 2, cq = rem & 3;

    const int t = threadIdx.x;
    const int tx = t & 63, ty = t >> 6;
    const int c0 = cq * 64 + ty * 16;

    float acc[NOFF];
#pragma unroll
    for (int q = 0; q < NOFF; ++q) acc[q] = 0.f;

    const float* xp = x + ((size_t)(b * C_) + c0) * HW;
    for (int ci = 0; ci < 16; ++ci) {
        float xv[9];
#pragma unroll
        for (int ky = 0; ky < 3; ++ky) {
            const int row = h + ky - 1;
            const bool rv = (row >= 0) && (row < H_);
            const int rowc = min(max(row, 0), H_ - 1);
#pragma unroll
            for (int kx = 0; kx < 3; ++kx) {
                const int col = tx + kx - 1;
                const bool cv = (col >= 0) && (col < W_);
                const int colc = min(max(col, 0), W_ - 1);
                const float v = xp[(size_t)ci * HW + rowc * W_ + colc];
                xv[ky * 3 + kx] = (rv && cv) ? v : 0.f;
            }
        }
        const float4* wv = (const float4*)(wt_off + (size_t)(c0 + ci) * 180);
#pragma unroll
        for (int kk = 0; kk < 9; ++kk) {
            float wreg[20];
            const float4* wk = wv + kk * 5;
#pragma unroll
            for (int q = 0; q < 5; ++q) {
                const float4 f = wk[q];
                wreg[q * 4 + 0] = f.x; wreg[q * 4 + 1] = f.y;
                wreg[q * 4 + 2] = f.z; wreg[q * 4 + 3] = f.w;
            }
#pragma unroll
            for (int oc = 0; oc < NOFF; ++oc)
                acc[oc] += xv[kk] * wreg[oc];
        }
    }

    __shared__ float red[4][64][NOFF];
#pragma unroll
    for (int oc = 0; oc < NOFF; ++oc) red[ty][tx][oc] = acc[oc];
    __syncthreads();

    for (int idx = t; idx < 64 * NOFF; idx += 256) {
        const int px = idx / NOFF, oc = idx % NOFF;
        const float s = red[0][px][oc] + red[1][px][oc] +
                        red[2][px][oc] + red[3][px][oc];
        part[(size_t)cq * (B_ * HW * NOFF) +
             ((size_t)(b * HW) + h * 64 + px) * NOFF + oc] = s;
    }
}

// ---------------------------------------------------------------------------
// Kernel 1b: reduce the 4 channel-quarter partials + bias -> offs
// ---------------------------------------------------------------------------
__global__ __launch_bounds__(256) void offs_reduce_kernel(
    const float* __restrict__ part, const float* __restrict__ b_off,
    float* __restrict__ offs)
{
    const int id = blockIdx.x * 256 + threadIdx.x;   // < 294912
    const size_t P = (size_t)B_ * HW * NOFF;
    const float s = part[id] + part[id + P] + part[id + 2 * P] + part[id + 3 * P];
    offs[id] = s + b_off[id % NOFF];
}

// ---------------------------------------------------------------------------
// Kernel 2: fused bilinear sampling + bf16 MFMA contraction.
// 256 blocks (XCD-swizzled), 512 threads (8 waves). Block tile 256o x 64p.
// Wave tile 64o x 32p = 4x2 frags of 16x16x32. 36 chunks (kk, 64c) x 2 ksteps.
// ---------------------------------------------------------------------------
__global__ __launch_bounds__(512, 2) void deform_mfma_kernel(
    const float* __restrict__ x, const float* __restrict__ offs,
    const uint4* __restrict__ Wt4, const float* __restrict__ b_def,
    float* __restrict__ out)
{
    __shared__ uint4 Wl4[2048];   // [256 o][8 gran], granule pos = g ^ (o&7)
    __shared__ uint4 Sl4[512];    // [64 p][8 gran], granule pos = g ^ (p&7)

    // bijective XCD swizzle: XCD (i&7) gets 32 contiguous (b,h) blocks
    const int i = blockIdx.x;
    const int l = ((i & 7) << 5) + (i >> 3);
    const int b = l >> 6, h = l & 63;

    const int t = threadIdx.x;
    const int lane = t & 63;
    const int w = t >> 6;
    const int wo = w >> 1, wp = w & 1;
    const int l15 = lane & 15, l4 = lane >> 4;

    const int sp = t & 63;          // staging pixel
    const int sg = t >> 6;          // staging c-granule (0..7)

    const float* xb = x + (size_t)b * C_ * HW;
    const float* ob = offs + ((size_t)(b * HW) + h * 64 + sp) * NOFF;

    f32x4 acc[4][2];
#pragma unroll
    for (int ii = 0; ii < 4; ++ii)
#pragma unroll
        for (int j = 0; j < 2; ++j) acc[ii][j] = f32x4{0.f, 0.f, 0.f, 0.f};

    for (int ch = 0; ch < 36; ++ch) {
        const int kk = ch >> 2, cg = ch & 3;
        __syncthreads();            // previous chunk's reads done
        // ---- stage W (pre-swizzled linear image: straight copy) ----
        const uint4* wsrc = Wt4 + (size_t)ch * 2048;
#pragma unroll
        for (int r = 0; r < 4; ++r)
            Wl4[t + 512 * r] = wsrc[t + 512 * r];
        // ---- bilinear meta for (kk, sp), recomputed per chunk ----
        const int ky = kk / 3, kx = kk - 3 * ky;
        const float dy = ob[2 * kk], dx = ob[2 * kk + 1];
        const float py = (float)(h + ky - 1) + dy;
        const float px = (float)(sp + kx - 1) + dx;
        const float y0f = floorf(py), x0f = floorf(px);
        const float ly = py - y0f, lx = px - x0f;
        const int y0 = (int)y0f, x0 = (int)x0f;
        const int y1 = y0 + 1, x1 = x0 + 1;
        const bool vy0 = (y0 >= 0) && (y0 < H_), vy1 = (y1 >= 0) && (y1 < H_);
        const bool vx0 = (x0 >= 0) && (x0 < W_), vx1 = (x1 >= 0) && (x1 < W_);
        const int y0c = min(max(y0, 0), H_ - 1), y1c = min(max(y1, 0), H_ - 1);
        const int x0c = min(max(x0, 0), W_ - 1), x1c = min(max(x1, 0), W_ - 1);
        const int i0 = y0c * W_ + x0c, i1 = y0c * W_ + x1c;
        const int i2 = y1c * W_ + x0c, i3 = y1c * W_ + x1c;
        const float w0 = (vy0 && vx0) ? (1.f - ly) * (1.f - lx) : 0.f;
        const float w1 = (vy0 && vx1) ? (1.f - ly) * lx : 0.f;
        const float w2 = (vy1 && vx0) ? ly * (1.f - lx) : 0.f;
        const float w3 = (vy1 && vx1) ? ly * lx : 0.f;
        // ---- stage S: 8 channels for (sp, kk) ----
        const float* pl = xb + (size_t)(cg * 64 + sg * 8) * HW;
        bf16x8 sv;
#pragma unroll
        for (int j = 0; j < 8; ++j) {
            const float* p = pl + (size_t)j * HW;
            const float v = w0 * p[i0] + w1 * p[i1] + w2 * p[i2] + w3 * p[i3];
            sv[j] = (__bf16)v;
        }
        Sl4[sp * 8 + (sg ^ (sp & 7))] = __builtin_bit_cast(uint4, sv);
        __syncthreads();            // staging visible
        // ---- compute: 2 K-steps of 32 ----
#pragma unroll
        for (int st = 0; st < 2; ++st) {
            const int g = st * 4 + l4;
            bf16x8 aF[4], bF[2];
#pragma unroll
            for (int ii = 0; ii < 4; ++ii) {
                const int row = wo * 64 + ii * 16 + l15;
                aF[ii] = __builtin_bit_cast(bf16x8, Wl4[row * 8 + (g ^ (row & 7))]);
            }
#pragma unroll
            for (int j = 0; j < 2; ++j) {
                const int pr = wp * 32 + j * 16 + l15;
                bF[j] = __builtin_bit_cast(bf16x8, Sl4[pr * 8 + (g ^ (pr & 7))]);
            }
#pragma unroll
            for (int ii = 0; ii < 4; ++ii)
#pragma unroll
                for (int j = 0; j < 2; ++j)
                    acc[ii][j] = __builtin_amdgcn_mfma_f32_16x16x32_bf16(
                        aF[ii], bF[j], acc[ii][j], 0, 0, 0);
        }
    }
    // ---- epilogue: bias + store (C/D: row=(l>>4)*4+r, col=l&15) ----
#pragma unroll
    for (int ii = 0; ii < 4; ++ii) {
#pragma unroll
        for (int r = 0; r < 4; ++r) {
            const int o = wo * 64 + ii * 16 + l4 * 4 + r;
            const float bias = b_def[o];
#pragma unroll
            for (int j = 0; j < 2; ++j) {
                const int p = wp * 32 + j * 16 + l15;
                out[(((size_t)(b * O_ + o)) * H_ + h) * W_ + p] = acc[ii][j][r] + bias;
            }
        }
    }
}

// ---------------------------------------------------------------------------
extern "C" void kernel_launch(void* const* d_in, const int* in_sizes, int n_in,
                              void* d_out, int out_size, void* d_ws, size_t ws_size,
                              hipStream_t stream) {
    const float* x     = (const float*)d_in[0];
    const float* w_off = (const float*)d_in[1];
    const float* b_off = (const float*)d_in[2];
    const float* w_def = (const float*)d_in[3];
    const float* b_def = (const float*)d_in[4];
    float* out = (float*)d_out;

    // ws layout (floats): offs 294912 | part 4*294912 | wt_off 46080 | Wt4
    float* offs   = (float*)d_ws;
    float* part   = offs + (size_t)B_ * HW * NOFF;
    float* wt_off = part + (size_t)4 * B_ * HW * NOFF;
    uint4* Wt4    = (uint4*)(wt_off + 2304 * 20);   // 16B-aligned (offset 6082560 B)

    wprep_off_kernel<<<9, 256, 0, stream>>>(w_off, wt_off);
    wprep_def_kernel<<<36, 256, 0, stream>>>(w_def, Wt4);
    offset_conv_part_kernel<<<1024, 256, 0, stream>>>(x, wt_off, part);
    offs_reduce_kernel<<<1152, 256, 0, stream>>>(part, b_off, offs);
    deform_mfma_kernel<<<256, 512, 0, stream>>>(x, offs, Wt4, b_def, out);
}

// Round 4
// 156.480 us; speedup vs baseline: 4.0953x; 2.0032x over previous
//
#include <hip/hip_runtime.h>

#define B_ 4
#define C_ 256
#define O_ 256
#define H_ 64
#define W_ 64
#define HW 4096
#define NOFF 18
#define CK 2304

typedef __bf16 bf16x8 __attribute__((ext_vector_type(8)));
typedef float f32x4 __attribute__((ext_vector_type(4)));

// ---------------------------------------------------------------------------
// wprep_def: pre-swizzled bf16 W image per (kk,cg) chunk.
// Wt4[ch*2048 + o*8 + (g^(o&7))] = bf16x8 of w_def[o][cg*64+g*8+j][kk]
// grid 288 x 256 (one granule per thread)
// ---------------------------------------------------------------------------
__global__ __launch_bounds__(256) void wprep_def_kernel(
    const float* __restrict__ w_def, uint4* __restrict__ Wt4)
{
    const int gidx = blockIdx.x * 256 + threadIdx.x;   // 0..73727
    const int ch = gidx >> 11;                         // 0..35
    const int rem = gidx & 2047;
    const int o = rem >> 3, g = rem & 7;
    const int kk = ch >> 2, cg = ch & 3;
    bf16x8 v;
#pragma unroll
    for (int j = 0; j < 8; ++j) {
        const int c = cg * 64 + g * 8 + j;
        v[j] = (__bf16)w_def[(size_t)o * CK + c * 9 + kk];
    }
    Wt4[(size_t)ch * 2048 + o * 8 + (g ^ (o & 7))] = __builtin_bit_cast(uint4, v);
}

// ---------------------------------------------------------------------------
// wprep_woff: offset-conv weights, bf16, M padded 18->32, same swizzle.
// Woff4[ch*256 + o*8 + (g^(o&7))]; grid 36 x 256
// ---------------------------------------------------------------------------
__global__ __launch_bounds__(256) void wprep_woff_kernel(
    const float* __restrict__ w_off, uint4* __restrict__ Woff4)
{
    const int ch = blockIdx.x;                 // 0..35
    const int t = threadIdx.x;                 // 0..255
    const int o = t >> 3, g = t & 7;           // o 0..31
    const int kk = ch >> 2, cg = ch & 3;
    bf16x8 v;
#pragma unroll
    for (int j = 0; j < 8; ++j) {
        const int c = cg * 64 + g * 8 + j;
        v[j] = (o < NOFF) ? (__bf16)w_off[(size_t)o * CK + c * 9 + kk] : (__bf16)0.f;
    }
    Woff4[(size_t)ch * 256 + o * 8 + (g ^ (o & 7))] = __builtin_bit_cast(uint4, v);
}

// ---------------------------------------------------------------------------
// Fused kernel: phase A = offset conv via MFMA (zero-offset sampling),
// phase B = bilinear sampling from LDS slab + deform MFMA.
// grid 256 (XCD-swizzled (b,h)), 512 threads (8 waves), 1 block/CU.
// ---------------------------------------------------------------------------
__global__ __launch_bounds__(512, 1) void deform_fused_kernel(
    const float* __restrict__ x, const uint4* __restrict__ Wt4,
    const uint4* __restrict__ Woff4, const float* __restrict__ b_off,
    const float* __restrict__ b_def, float* __restrict__ out)
{
    __shared__ uint4 slab[4096];        // 64KB: [8 rows][64 col][8 gran], gran=g^(col&7), bf16 x8
    __shared__ uint4 Wl4[2048];         // 32KB: deform W chunk
    __shared__ uint4 Sl4[512];          //  8KB: sampled B chunk
    __shared__ uint4 woff_lds[256];     //  4KB: offset-conv W chunk
    __shared__ float offs_lds[NOFF * 64]; // 4.5KB: predicted offsets [oc][px]

    // bijective XCD swizzle: XCD (i&7) owns 32 contiguous (b,h) blocks
    const int i = blockIdx.x;
    const int l = ((i & 7) << 5) + (i >> 3);
    const int b = l >> 6, h = l & 63;
    const int wb = h - 3;               // slab window rows [wb, wb+7]

    const int t = threadIdx.x;
    const int lane = t & 63;
    const int w = t >> 6;               // wave id 0..7
    const int l15 = lane & 15, l4 = lane >> 4;
    const int sp = t & 63;              // staging pixel
    const int sg = w;                   // staging channel-granule
    const float* xb = x + (size_t)b * C_ * HW;

    auto stage_slab = [&](int cg) {
        const float* xc = xb + (size_t)(cg * 64 + sg * 8) * HW;
#pragma unroll
        for (int r = 0; r < 8; ++r) {
            const int yc = min(max(wb + r, 0), H_ - 1);
            bf16x8 v;
#pragma unroll
            for (int j = 0; j < 8; ++j)
                v[j] = (__bf16)xc[(size_t)j * HW + yc * W_ + sp];
            slab[(r * 64 + sp) * 8 + (sg ^ (sp & 7))] = __builtin_bit_cast(uint4, v);
        }
    };

    // ======================= Phase A: offset conv =========================
    f32x4 acc_off0 = {0.f, 0.f, 0.f, 0.f}, acc_off1 = {0.f, 0.f, 0.f, 0.f};
    for (int cg = 0; cg < 4; ++cg) {
        stage_slab(cg);
        __syncthreads();                // slab visible
        for (int kk = 0; kk < 9; ++kk) {
            if (t < 256) woff_lds[t] = Woff4[(size_t)(kk * 4 + cg) * 256 + t];
            // S_off: plain shifted read with exact zero padding
            const int ky = kk / 3, kx = kk - 3 * ky;
            const int y = h + ky - 1;
            const int col = sp + kx - 1;
            uint4 sv = {0u, 0u, 0u, 0u};
            if (y >= 0 && y < H_ && col >= 0 && col < W_)
                sv = slab[((ky + 2) * 64 + col) * 8 + (sg ^ (col & 7))];
            Sl4[sp * 8 + (sg ^ (sp & 7))] = sv;
            __syncthreads();            // Sl4 / woff visible
            if (w < 4) {
#pragma unroll
                for (int st = 0; st < 2; ++st) {
                    const int g = st * 4 + l4;
                    const int pr = w * 16 + l15;
                    const bf16x8 bF = __builtin_bit_cast(bf16x8, Sl4[pr * 8 + (g ^ (pr & 7))]);
                    const int r0 = l15, r1 = 16 + l15;
                    const bf16x8 a0 = __builtin_bit_cast(bf16x8, woff_lds[r0 * 8 + (g ^ (r0 & 7))]);
                    const bf16x8 a1 = __builtin_bit_cast(bf16x8, woff_lds[r1 * 8 + (g ^ (r1 & 7))]);
                    acc_off0 = __builtin_amdgcn_mfma_f32_16x16x32_bf16(a0, bF, acc_off0, 0, 0, 0);
                    acc_off1 = __builtin_amdgcn_mfma_f32_16x16x32_bf16(a1, bF, acc_off1, 0, 0, 0);
                }
            }
            __syncthreads();            // buffers free for next kk / next cg
        }
    }
    // offsets -> LDS (C/D layout: row = l4*4+r, col = l15; wave w = px quarter)
    if (w < 4) {
#pragma unroll
        for (int ii = 0; ii < 2; ++ii) {
            const f32x4 a = ii ? acc_off1 : acc_off0;
#pragma unroll
            for (int r = 0; r < 4; ++r) {
                const int oc = ii * 16 + l4 * 4 + r;
                if (oc < NOFF)
                    offs_lds[oc * 64 + (w * 16 + l15)] = a[r] + b_off[oc];
            }
        }
    }
    __syncthreads();

    // ======================= Phase B: deform conv =========================
    const int wo = w >> 1, wp = w & 1;
    f32x4 acc[4][2];
#pragma unroll
    for (int ii = 0; ii < 4; ++ii)
#pragma unroll
        for (int j = 0; j < 2; ++j) acc[ii][j] = f32x4{0.f, 0.f, 0.f, 0.f};

    for (int cgi = 0; cgi < 4; ++cgi) {
        const int cg = 3 - cgi;         // cg=3 slab is still resident from phase A
        if (cgi != 0) {
            stage_slab(cg);
            __syncthreads();
        }
        const float* xsg = xb + (size_t)(cg * 64 + sg * 8) * HW;  // slow-path base
        for (int kk = 0; kk < 9; ++kk) {
            // ---- stage deform W chunk (pre-swizzled: straight copy) ----
            const uint4* wsrc = Wt4 + (size_t)(kk * 4 + cg) * 2048;
#pragma unroll
            for (int r = 0; r < 4; ++r)
                Wl4[t + 512 * r] = wsrc[t + 512 * r];
            // ---- bilinear meta ----
            const int ky = kk / 3, kx = kk - 3 * ky;
            const float dy = offs_lds[(2 * kk) * 64 + sp];
            const float dx = offs_lds[(2 * kk + 1) * 64 + sp];
            const float py = (float)(h + ky - 1) + dy;
            const float pxf = (float)(sp + kx - 1) + dx;
            const float y0f = floorf(py), x0f = floorf(pxf);
            const float ly = py - y0f, lx = pxf - x0f;
            const int y0 = (int)y0f, x0 = (int)x0f;
            const int y1 = y0 + 1, x1 = x0 + 1;
            const bool vy0 = (y0 >= 0) && (y0 < H_), vy1 = (y1 >= 0) && (y1 < H_);
            const bool vx0 = (x0 >= 0) && (x0 < W_), vx1 = (x1 >= 0) && (x1 < W_);
            const float w00 = (vy0 && vx0) ? (1.f - ly) * (1.f - lx) : 0.f;
            const float w01 = (vy0 && vx1) ? (1.f - ly) * lx : 0.f;
            const float w10 = (vy1 && vx0) ? ly * (1.f - lx) : 0.f;
            const float w11 = (vy1 && vx1) ? ly * lx : 0.f;
            bf16x8 sv;
            if (y0 >= wb && y0 <= wb + 6) {
                // ---- fast path: 4 corners from LDS slab ----
                const int s0 = y0 - wb;
                const int xc0 = min(max(x0, 0), W_ - 1);
                const int xc1 = min(max(x1, 0), W_ - 1);
                const int gx0 = sg ^ (xc0 & 7), gx1 = sg ^ (xc1 & 7);
                const bf16x8 c00 = __builtin_bit_cast(bf16x8, slab[(s0 * 64 + xc0) * 8 + gx0]);
                const bf16x8 c01 = __builtin_bit_cast(bf16x8, slab[(s0 * 64 + xc1) * 8 + gx1]);
                const bf16x8 c10 = __builtin_bit_cast(bf16x8, slab[((s0 + 1) * 64 + xc0) * 8 + gx0]);
                const bf16x8 c11 = __builtin_bit_cast(bf16x8, slab[((s0 + 1) * 64 + xc1) * 8 + gx1]);
#pragma unroll
                for (int j = 0; j < 8; ++j) {
                    const float v = w00 * (float)c00[j] + w01 * (float)c01[j]
                                  + w10 * (float)c10[j] + w11 * (float)c11[j];
                    sv[j] = (__bf16)v;
                }
            } else {
                // ---- slow path (offset beyond slab window; ~never) ----
                const int y0c = min(max(y0, 0), H_ - 1), y1c = min(max(y1, 0), H_ - 1);
                const int xc0 = min(max(x0, 0), W_ - 1), xc1 = min(max(x1, 0), W_ - 1);
                const int i00 = y0c * W_ + xc0, i01 = y0c * W_ + xc1;
                const int i10 = y1c * W_ + xc0, i11 = y1c * W_ + xc1;
#pragma unroll
                for (int j = 0; j < 8; ++j) {
                    const float* p = xsg + (size_t)j * HW;
                    const float v = w00 * p[i00] + w01 * p[i01]
                                  + w10 * p[i10] + w11 * p[i11];
                    sv[j] = (__bf16)v;
                }
            }
            Sl4[sp * 8 + (sg ^ (sp & 7))] = __builtin_bit_cast(uint4, sv);
            __syncthreads();            // Wl4 / Sl4 visible
            // ---- 2 K-steps of MFMA ----
#pragma unroll
            for (int st = 0; st < 2; ++st) {
                const int g = st * 4 + l4;
                bf16x8 aF[4], bF[2];
#pragma unroll
                for (int ii = 0; ii < 4; ++ii) {
                    const int row = wo * 64 + ii * 16 + l15;
                    aF[ii] = __builtin_bit_cast(bf16x8, Wl4[row * 8 + (g ^ (row & 7))]);
                }
#pragma unroll
                for (int j = 0; j < 2; ++j) {
                    const int pr = wp * 32 + j * 16 + l15;
                    bF[j] = __builtin_bit_cast(bf16x8, Sl4[pr * 8 + (g ^ (pr & 7))]);
                }
#pragma unroll
                for (int ii = 0; ii < 4; ++ii)
#pragma unroll
                    for (int j = 0; j < 2; ++j)
                        acc[ii][j] = __builtin_amdgcn_mfma_f32_16x16x32_bf16(
                            aF[ii], bF[j], acc[ii][j], 0, 0, 0);
            }
            __syncthreads();            // buffers free
        }
    }

    // ---- epilogue: bias + store (C/D: row=(l>>4)*4+r, col=l&15) ----
#pragma unroll
    for (int ii = 0; ii < 4; ++ii) {
#pragma unroll
        for (int r = 0; r < 4; ++r) {
            const int o = wo * 64 + ii * 16 + l4 * 4 + r;
            const float bias = b_def[o];
#pragma unroll
            for (int j = 0; j < 2; ++j) {
                const int p = wp * 32 + j * 16 + l15;
                out[(((size_t)(b * O_ + o)) * H_ + h) * W_ + p] = acc[ii][j][r] + bias;
            }
        }
    }
}

// ---------------------------------------------------------------------------
extern "C" void kernel_launch(void* const* d_in, const int* in_sizes, int n_in,
                              void* d_out, int out_size, void* d_ws, size_t ws_size,
                              hipStream_t stream) {
    const float* x     = (const float*)d_in[0];
    const float* w_off = (const float*)d_in[1];
    const float* b_off = (const float*)d_in[2];
    const float* w_def = (const float*)d_in[3];
    const float* b_def = (const float*)d_in[4];
    float* out = (float*)d_out;

    // ws layout: Wt4 (73728 uint4 = 1.125 MB) | Woff4 (9216 uint4 = 144 KB)
    uint4* Wt4   = (uint4*)d_ws;
    uint4* Woff4 = Wt4 + 73728;

    wprep_def_kernel<<<288, 256, 0, stream>>>(w_def, Wt4);
    wprep_woff_kernel<<<36, 256, 0, stream>>>(w_off, Woff4);
    deform_fused_kernel<<<256, 512, 0, stream>>>(x, Wt4, Woff4, b_off, b_def, out);
}

// Round 7
// 149.477 us; speedup vs baseline: 4.2871x; 1.0469x over previous
//
#include <hip/hip_runtime.h>

#define B_ 4
#define C_ 256
#define O_ 256
#define H_ 64
#define W_ 64
#define HW 4096
#define NOFF 18
#define CK 2304

typedef __bf16 bf16x8 __attribute__((ext_vector_type(8)));
typedef float f32x4 __attribute__((ext_vector_type(4)));

// ---------------------------------------------------------------------------
// wprep_def (coalesced): one block per output row o.
// Phase 1: read w_def[o][*] (2304 f32) -> LDS bf16.
// Phase 2: scatter 288 pre-swizzled uint4 granules (36 ch x 8 g) to Wt4.
// Wt4[ch*2048 + o*8 + (g^(o&7))], ch = kk*4+cg, granule ch c = cg*64+g*8+j.
// FIX r6: strided loop covers all 288 granules (r5's `if(t<288)` with 256
// threads left ch=32..35, i.e. the whole kk=8 tap, unwritten -> poison).
// ---------------------------------------------------------------------------
__global__ __launch_bounds__(256) void wprep_def_kernel(
    const float* __restrict__ w_def, uint4* __restrict__ Wt4)
{
    __shared__ __bf16 wrow[CK];
    const int o = blockIdx.x;
    const int t = threadIdx.x;
#pragma unroll
    for (int q = 0; q < 9; ++q)
        wrow[t * 9 + q] = (__bf16)w_def[(size_t)o * CK + t * 9 + q];
    __syncthreads();
    for (int s = t; s < 288; s += 256) {
        const int ch = s >> 3, g = s & 7;
        const int kk = ch >> 2, cg = ch & 3;
        bf16x8 v;
#pragma unroll
        for (int j = 0; j < 8; ++j)
            v[j] = wrow[(cg * 64 + g * 8 + j) * 9 + kk];
        Wt4[(size_t)ch * 2048 + o * 8 + (g ^ (o & 7))] = __builtin_bit_cast(uint4, v);
    }
}

// ---------------------------------------------------------------------------
// wprep_woff: offset-conv weights, bf16, M padded 18->32, same swizzle.
// Woff4[ch*256 + o*8 + (g^(o&7))]; grid 36 x 256
// ---------------------------------------------------------------------------
__global__ __launch_bounds__(256) void wprep_woff_kernel(
    const float* __restrict__ w_off, uint4* __restrict__ Woff4)
{
    const int ch = blockIdx.x;                 // 0..35
    const int t = threadIdx.x;
    const int o = t >> 3, g = t & 7;           // o 0..31
    const int kk = ch >> 2, cg = ch & 3;
    bf16x8 v;
#pragma unroll
    for (int j = 0; j < 8; ++j) {
        const int c = cg * 64 + g * 8 + j;
        v[j] = (o < NOFF) ? (__bf16)w_off[(size_t)o * CK + c * 9 + kk] : (__bf16)0.f;
    }
    Woff4[(size_t)ch * 256 + o * 8 + (g ^ (o & 7))] = __builtin_bit_cast(uint4, v);
}

// ---------------------------------------------------------------------------
// Offset conv via MFMA, barrier-free main loop.
// grid 512 = (b,h,px-half) XCD-swizzled; 256 threads = 4 waves.
// wave w: px-16-group (w&1), K-half (w>>1). B-frags gathered from global x.
// One LDS reduce at the end combines K-halves. offs[bh*64+px][18] f32.
// ---------------------------------------------------------------------------
__global__ __launch_bounds__(256, 4) void offs_mfma_kernel(
    const float* __restrict__ x, const uint4* __restrict__ Woff4,
    const float* __restrict__ b_off, float* __restrict__ offs)
{
    __shared__ float red[2][32][16];

    const int i = blockIdx.x;
    const int l = ((i & 7) << 6) + (i >> 3);   // bijective, 64 blocks/XCD
    const int ph = l & 1;                      // px half
    const int bh = l >> 1;
    const int b = bh >> 6, h = bh & 63;

    const int t = threadIdx.x;
    const int w = t >> 6, lane = t & 63;
    const int l15 = lane & 15, l4 = lane >> 4;
    const int pxg = w & 1, kh = w >> 1;
    const int px = ph * 32 + pxg * 16 + l15;   // this lane's pixel (B-frag col)
    const float* xb = x + (size_t)b * C_ * HW;

    f32x4 acc0 = {0.f, 0.f, 0.f, 0.f}, acc1 = {0.f, 0.f, 0.f, 0.f};

    for (int kk = 0; kk < 9; ++kk) {
        const int ky = kk / 3, kx = kk - 3 * ky;
        const int y = h + ky - 1;
        const int col = px + kx - 1;
        const bool valid = (y >= 0) && (y < H_) && (col >= 0) && (col < W_);
#pragma unroll
        for (int cgl = 0; cgl < 2; ++cgl) {
            const int cg = kh * 2 + cgl;
            const int ch = kk * 4 + cg;
#pragma unroll
            for (int st = 0; st < 2; ++st) {
                const int g = st * 4 + l4;
                const int r0 = l15, r1 = 16 + l15;
                const bf16x8 a0 = __builtin_bit_cast(bf16x8,
                    Woff4[(size_t)ch * 256 + r0 * 8 + (g ^ (r0 & 7))]);
                const bf16x8 a1 = __builtin_bit_cast(bf16x8,
                    Woff4[(size_t)ch * 256 + r1 * 8 + (g ^ (r1 & 7))]);
                bf16x8 bF;
                if (valid) {
                    const float* p = xb + (size_t)(cg * 64 + g * 8) * HW + y * W_ + col;
#pragma unroll
                    for (int j = 0; j < 8; ++j)
                        bF[j] = (__bf16)p[(size_t)j * HW];
                } else {
#pragma unroll
                    for (int j = 0; j < 8; ++j) bF[j] = (__bf16)0.f;
                }
                acc0 = __builtin_amdgcn_mfma_f32_16x16x32_bf16(a0, bF, acc0, 0, 0, 0);
                acc1 = __builtin_amdgcn_mfma_f32_16x16x32_bf16(a1, bF, acc1, 0, 0, 0);
            }
        }
    }

    // K-half reduce: waves 2,3 park partials; waves 0,1 finalize.
    if (kh == 1) {
#pragma unroll
        for (int r = 0; r < 4; ++r) {
            red[pxg][l4 * 4 + r][l15] = acc0[r];
            red[pxg][16 + l4 * 4 + r][l15] = acc1[r];
        }
    }
    __syncthreads();
    if (kh == 0) {
#pragma unroll
        for (int ii = 0; ii < 2; ++ii) {
            const f32x4 a = ii ? acc1 : acc0;
#pragma unroll
            for (int r = 0; r < 4; ++r) {
                const int oc = ii * 16 + l4 * 4 + r;
                if (oc < NOFF) {
                    const float v = a[r] + red[pxg][oc][l15] + b_off[oc];
                    offs[((size_t)(bh * 64) + px) * NOFF + oc] = v;
                }
            }
        }
    }
}

// ---------------------------------------------------------------------------
// Deform conv: bilinear sampling from LDS slab + bf16 MFMA.
// grid 512 = (b,h,o-half) XCD-swizzled; 512 threads (8 waves), 2 blocks/CU.
// Block tile 128o x 64px; wave tile 32o x 32px (2x2 frags).
// A-frags direct from pre-swizzled global Wt4 (no LDS stage).
// ---------------------------------------------------------------------------
__global__ __launch_bounds__(512, 4) void deform_mfma_kernel(
    const float* __restrict__ x, const float* __restrict__ offs,
    const uint4* __restrict__ Wt4, const float* __restrict__ b_def,
    float* __restrict__ out)
{
    __shared__ uint4 slab[4096];          // 64KB [8 rows][64 col][8 gran], gran=g^(col&7)
    __shared__ uint4 Sl4[512];            //  8KB sampled chunk [64 px][8 gran]
    __shared__ float offs_lds[NOFF * 64]; // 4.5KB [oc][px]

    const int i = blockIdx.x;
    const int l = ((i & 7) << 6) + (i >> 3);   // 64 blocks/XCD; pairs share (b,h)
    const int oh = l & 1;
    const int bh = l >> 1;
    const int b = bh >> 6, h = bh & 63;
    const int obase = oh * 128;
    const int wb = h - 3;                 // slab window rows [wb, wb+7]

    const int t = threadIdx.x;
    const int lane = t & 63;
    const int w = t >> 6;
    const int wo = w >> 1, wp = w & 1;
    const int l15 = lane & 15, l4 = lane >> 4;
    const int sp = t & 63;                // staging pixel
    const int sg = w;                     // staging channel-granule
    const float* xb = x + (size_t)b * C_ * HW;

    auto stage_slab = [&](int cg) {
        const float* xc = xb + (size_t)(cg * 64 + sg * 8) * HW;
#pragma unroll
        for (int r = 0; r < 8; ++r) {
            const int yc = min(max(wb + r, 0), H_ - 1);
            bf16x8 v;
#pragma unroll
            for (int j = 0; j < 8; ++j)
                v[j] = (__bf16)xc[(size_t)j * HW + yc * W_ + sp];
            slab[(r * 64 + sp) * 8 + (sg ^ (sp & 7))] = __builtin_bit_cast(uint4, v);
        }
    };

    // ---- stage offsets + first slab ----
    for (int idx = t; idx < NOFF * 64; idx += 512) {
        const int px = idx & 63, oc = idx >> 6;
        offs_lds[oc * 64 + px] = offs[((size_t)(bh * 64) + px) * NOFF + oc];
    }
    stage_slab(0);

    f32x4 acc[2][2];
#pragma unroll
    for (int ii = 0; ii < 2; ++ii)
#pragma unroll
        for (int j = 0; j < 2; ++j) acc[ii][j] = f32x4{0.f, 0.f, 0.f, 0.f};

    for (int cg = 0; cg < 4; ++cg) {
        if (cg != 0) stage_slab(cg);
        __syncthreads();                  // slab (+offs on cg=0) visible
        const float* xsg = xb + (size_t)(cg * 64 + sg * 8) * HW;  // slow-path base
        for (int kk = 0; kk < 9; ++kk) {
            const int ch = kk * 4 + cg;
            // ---- A-frags direct from global (issue early, hide under sampling) ----
            uint4 aR[2][2];
#pragma unroll
            for (int st = 0; st < 2; ++st) {
                const int g = st * 4 + l4;
#pragma unroll
                for (int ii = 0; ii < 2; ++ii) {
                    const int row = obase + wo * 32 + ii * 16 + l15;
                    aR[st][ii] = Wt4[(size_t)ch * 2048 + row * 8 + (g ^ (row & 7))];
                }
            }
            // ---- bilinear sampling for (kk, sp), granule sg ----
            const int ky = kk / 3, kx = kk - 3 * ky;
            const float dy = offs_lds[(2 * kk) * 64 + sp];
            const float dx = offs_lds[(2 * kk + 1) * 64 + sp];
            const float py = (float)(h + ky - 1) + dy;
            const float pxf = (float)(sp + kx - 1) + dx;
            const float y0f = floorf(py), x0f = floorf(pxf);
            const float ly = py - y0f, lx = pxf - x0f;
            const int y0 = (int)y0f, x0 = (int)x0f;
            const int y1 = y0 + 1, x1 = x0 + 1;
            const bool vy0 = (y0 >= 0) && (y0 < H_), vy1 = (y1 >= 0) && (y1 < H_);
            const bool vx0 = (x0 >= 0) && (x0 < W_), vx1 = (x1 >= 0) && (x1 < W_);
            const float w00 = (vy0 && vx0) ? (1.f - ly) * (1.f - lx) : 0.f;
            const float w01 = (vy0 && vx1) ? (1.f - ly) * lx : 0.f;
            const float w10 = (vy1 && vx0) ? ly * (1.f - lx) : 0.f;
            const float w11 = (vy1 && vx1) ? ly * lx : 0.f;
            bf16x8 sv;
            if (y0 >= wb && y0 <= wb + 6) {
                const int s0 = y0 - wb;
                const int xc0 = min(max(x0, 0), W_ - 1);
                const int xc1 = min(max(x1, 0), W_ - 1);
                const int gx0 = sg ^ (xc0 & 7), gx1 = sg ^ (xc1 & 7);
                const bf16x8 c00 = __builtin_bit_cast(bf16x8, slab[(s0 * 64 + xc0) * 8 + gx0]);
                const bf16x8 c01 = __builtin_bit_cast(bf16x8, slab[(s0 * 64 + xc1) * 8 + gx1]);
                const bf16x8 c10 = __builtin_bit_cast(bf16x8, slab[((s0 + 1) * 64 + xc0) * 8 + gx0]);
                const bf16x8 c11 = __builtin_bit_cast(bf16x8, slab[((s0 + 1) * 64 + xc1) * 8 + gx1]);
#pragma unroll
                for (int j = 0; j < 8; ++j) {
                    const float v = w00 * (float)c00[j] + w01 * (float)c01[j]
                                  + w10 * (float)c10[j] + w11 * (float)c11[j];
                    sv[j] = (__bf16)v;
                }
            } else {
                const int y0c = min(max(y0, 0), H_ - 1), y1c = min(max(y1, 0), H_ - 1);
                const int xc0 = min(max(x0, 0), W_ - 1), xc1 = min(max(x1, 0), W_ - 1);
                const int i00 = y0c * W_ + xc0, i01 = y0c * W_ + xc1;
                const int i10 = y1c * W_ + xc0, i11 = y1c * W_ + xc1;
#pragma unroll
                for (int j = 0; j < 8; ++j) {
                    const float* p = xsg + (size_t)j * HW;
                    const float v = w00 * p[i00] + w01 * p[i01]
                                  + w10 * p[i10] + w11 * p[i11];
                    sv[j] = (__bf16)v;
                }
            }
            __syncthreads();              // previous chunk's Sl4 reads complete
            Sl4[sp * 8 + (sg ^ (sp & 7))] = __builtin_bit_cast(uint4, sv);
            __syncthreads();              // Sl4 visible
            // ---- 2 K-steps of MFMA ----
#pragma unroll
            for (int st = 0; st < 2; ++st) {
                const int g = st * 4 + l4;
                bf16x8 bF[2];
#pragma unroll
                for (int j = 0; j < 2; ++j) {
                    const int pr = wp * 32 + j * 16 + l15;
                    bF[j] = __builtin_bit_cast(bf16x8, Sl4[pr * 8 + (g ^ (pr & 7))]);
                }
#pragma unroll
                for (int ii = 0; ii < 2; ++ii)
#pragma unroll
                    for (int j = 0; j < 2; ++j)
                        acc[ii][j] = __builtin_amdgcn_mfma_f32_16x16x32_bf16(
                            __builtin_bit_cast(bf16x8, aR[st][ii]), bF[j],
                            acc[ii][j], 0, 0, 0);
            }
        }
        __syncthreads();                  // all sampling reads of slab done
    }

    // ---- epilogue: bias + store (C/D: row=(l>>4)*4+r, col=l&15) ----
#pragma unroll
    for (int ii = 0; ii < 2; ++ii) {
#pragma unroll
        for (int r = 0; r < 4; ++r) {
            const int o = obase + wo * 32 + ii * 16 + l4 * 4 + r;
            const float bias = b_def[o];
#pragma unroll
            for (int j = 0; j < 2; ++j) {
                const int p = wp * 32 + j * 16 + l15;
                out[(((size_t)(b * O_ + o)) * H_ + h) * W_ + p] = acc[ii][j][r] + bias;
            }
        }
    }
}

// ---------------------------------------------------------------------------
extern "C" void kernel_launch(void* const* d_in, const int* in_sizes, int n_in,
                              void* d_out, int out_size, void* d_ws, size_t ws_size,
                              hipStream_t stream) {
    const float* x     = (const float*)d_in[0];
    const float* w_off = (const float*)d_in[1];
    const float* b_off = (const float*)d_in[2];
    const float* w_def = (const float*)d_in[3];
    const float* b_def = (const float*)d_in[4];
    float* out = (float*)d_out;

    // ws: Wt4 (73728 uint4 = 1.125MB) | Woff4 (9216 uint4 = 144KB) | offs (1.18MB)
    uint4* Wt4   = (uint4*)d_ws;
    uint4* Woff4 = Wt4 + 73728;
    float* offs  = (float*)(Woff4 + 9216);

    wprep_def_kernel<<<256, 256, 0, stream>>>(w_def, Wt4);
    wprep_woff_kernel<<<36, 256, 0, stream>>>(w_off, Woff4);
    offs_mfma_kernel<<<512, 256, 0, stream>>>(x, Woff4, b_off, offs);
    deform_mfma_kernel<<<512, 512, 0, stream>>>(x, offs, Wt4, b_def, out);
}